// Round 1
// baseline (189.867 us; speedup 1.0000x reference)
//
#include <hip/hip_runtime.h>

// R7: attn rewritten around SWAPPED QK^T mfma(K,Q) -> S^T lane layout:
//  lane owns q = q0 + l15, k = t*16 + quad*4 + r  (k contiguous in reg idx r).
//  - dep blend: 32x ds_read_b128 float4 (was 128x scalar ds_read_b32)
//  - softmax: per-lane row-local; 2 shfl_xor (16,32) per reduction (was 16)
//  - epilogue: DIRECT float4 global stores; outL LDS transpose removed entirely
//  - dep-stage barrier deferred past the MFMA loop (stage latency hidden)
// proj/prep unchanged from R6 (128x128 LDS-tiled MFMA GEMM; Q pre-scaled 0.9/8).

typedef _Float16 f16;
typedef _Float16 f16x4 __attribute__((ext_vector_type(4)));
typedef _Float16 f16x8 __attribute__((ext_vector_type(8)));
typedef float    f32x4 __attribute__((ext_vector_type(4)));

#define NTOK   512
#define DMODEL 768
#define BATCH  8
#define NHEAD  12
#define NEGV   (-1e9f)
#define KPAD   72    // proj LDS row stride (halfs)
#define DEPS   516   // dep LDS row stride (floats): uniform per-bank demand for b128 reads

// ---------------------------------------------------------------------------
// prep: blocks [0,3072) convert X fp32->f16; blocks [3072,4224) transpose
// Wq/Wk 32x32 tiles -> Wt[n][k] f16 (rows 0-767 Wq^T, 768-1535 Wk^T).
__global__ __launch_bounds__(256)
void prep_kernel(const float* __restrict__ X, f16* __restrict__ Xh,
                 const float* __restrict__ Wq, const float* __restrict__ Wk,
                 f16* __restrict__ Wt) {
    const int bx = blockIdx.x;
    if (bx < 3072) {
        const size_t i = ((size_t)bx * 256 + threadIdx.x) * 4;
        float4 v = *(const float4*)&X[i];
        f16x4 h = { (f16)v.x, (f16)v.y, (f16)v.z, (f16)v.w };
        *(f16x4*)&Xh[i] = h;
    } else {
        __shared__ float tile[32][33];
        const int id = bx - 3072;
        const int kb = (id % 24) * 32;
        const int nb = (id / 24) * 32;
        const float* __restrict__ W = (nb < 768) ? Wq : Wk;
        const int nc = (nb < 768) ? nb : nb - 768;
        const int tx = threadIdx.x & 31, ty = threadIdx.x >> 5;
        #pragma unroll
        for (int i = 0; i < 4; ++i)
            tile[ty + i*8][tx] = W[(size_t)(kb + ty + i*8) * DMODEL + nc + tx];
        __syncthreads();
        #pragma unroll
        for (int i = 0; i < 4; ++i)
            Wt[(size_t)(nb + ty + i*8) * DMODEL + kb + tx] = (f16)tile[tx][ty + i*8];
    }
}

// ---------------------------------------------------------------------------
// proj: 128x128 tile per block, 4 waves in 2x2 quadrants, BK=64 LDS-staged.
// QK[4096][1536] = Xh * Wt^T + bias; Q columns (<768) pre-scaled by 0.9/8.
__global__ __launch_bounds__(256)
void proj_mfma(const f16* __restrict__ Xh, const f16* __restrict__ Wt,
               const float* __restrict__ bq, const float* __restrict__ bk,
               f16* __restrict__ QK) {
    const int m0 = blockIdx.x * 128;
    const int n0 = blockIdx.y * 128;
    const int tid = threadIdx.x;
    const int wid = tid >> 6, l = tid & 63;
    const int l15 = l & 15, quad = l >> 4;
    const int wm = (wid & 1) * 64;
    const int wn = (wid >> 1) * 64;

    __shared__ f16 As[128 * KPAD];
    __shared__ f16 Bs[128 * KPAD];

    f32x4 acc[4][4];
    #pragma unroll
    for (int i = 0; i < 4; ++i)
        #pragma unroll
        for (int j = 0; j < 4; ++j) acc[i][j] = (f32x4){0.f, 0.f, 0.f, 0.f};

    const int srow = tid >> 1;
    const int scol = (tid & 1) * 32;

    for (int kt = 0; kt < DMODEL; kt += 64) {
        const f16* __restrict__ Asrc = Xh + (size_t)(m0 + srow) * DMODEL + kt + scol;
        const f16* __restrict__ Bsrc = Wt + (size_t)(n0 + srow) * DMODEL + kt + scol;
        #pragma unroll
        for (int j = 0; j < 4; ++j) {
            f16x8 av = *(const f16x8*)(Asrc + j * 8);
            *(f16x8*)&As[srow * KPAD + scol + j * 8] = av;
        }
        #pragma unroll
        for (int j = 0; j < 4; ++j) {
            f16x8 bv = *(const f16x8*)(Bsrc + j * 8);
            *(f16x8*)&Bs[srow * KPAD + scol + j * 8] = bv;
        }
        __syncthreads();
        #pragma unroll
        for (int ks = 0; ks < 2; ++ks) {
            f16x8 a[4], b[4];
            #pragma unroll
            for (int mi = 0; mi < 4; ++mi)
                a[mi] = *(f16x8*)&As[(wm + mi*16 + l15) * KPAD + ks*32 + quad*8];
            #pragma unroll
            for (int ni = 0; ni < 4; ++ni)
                b[ni] = *(f16x8*)&Bs[(wn + ni*16 + l15) * KPAD + ks*32 + quad*8];
            #pragma unroll
            for (int mi = 0; mi < 4; ++mi)
                #pragma unroll
                for (int ni = 0; ni < 4; ++ni)
                    acc[mi][ni] = __builtin_amdgcn_mfma_f32_16x16x32_f16(
                        a[mi], b[ni], acc[mi][ni], 0, 0, 0);
        }
        __syncthreads();
    }

    const float SC = (1.0f - 0.1f) / 8.0f;
    #pragma unroll
    for (int ni = 0; ni < 4; ++ni) {
        const int col = n0 + wn + ni * 16 + l15;
        const bool isQ = (col < 768);
        const float bv = isQ ? bq[col] : bk[col - 768];
        const float sc = isQ ? SC : 1.0f;
        #pragma unroll
        for (int mi = 0; mi < 4; ++mi)
            #pragma unroll
            for (int r = 0; r < 4; ++r) {
                const int row = m0 + wm + mi * 16 + quad * 4 + r;
                QK[(size_t)row * 1536 + col] = (f16)((acc[mi][ni][r] + bv) * sc);
            }
    }
}

// ---------------------------------------------------------------------------
// attn: block = (b, qt, head-group); 384 thr = 6 waves, wave w -> head hg*6+w,
// 16 q-rows. SWAPPED mfma(K,Q): D[col=q=l15][row=k=quad*4+r], k-tile t adds 16t.
// Per lane: one q row, k = 16t + 4*quad + r  -> float4 dep reads, 2-shfl
// softmax, direct float4 stores. dep LDS tile shared by 6 heads; barrier
// deferred past MFMA. grid (32, 2, 8) = 512 blocks.
__global__ __launch_bounds__(384, 2)
void attn_mfma(const f16* __restrict__ QK, const float* __restrict__ dep,
               const int* __restrict__ mask, float* __restrict__ out) {
    const int qt = blockIdx.x;        // 0..31
    const int hg = blockIdx.y;        // 0..1
    const int b  = blockIdx.z;        // 0..7
    const int tid = threadIdx.x;
    const int wid = tid >> 6;         // 0..5
    const int l   = tid & 63;
    const int l15 = l & 15, quad = l >> 4;
    const int h  = hg * 6 + wid;
    const int q0 = qt * 16;

    __shared__ float depL[16 * DEPS];        // 33.0 KB (outL removed)

    // stage dep tile: 16 rows x 512 cols (2048 float4, block-cooperative).
    // NOTE: no barrier here -- deferred until after the MFMA loop, so the
    // HBM->LDS staging latency hides under 64 MFMAs.
    {
        const float* __restrict__ src = dep + ((size_t)b * NTOK + q0) * NTOK;
        #pragma unroll
        for (int i = 0; i < 6; ++i) {
            const int idx = tid + i * 384;
            if (idx < 2048) {
                const int row = idx >> 7, c4 = idx & 127;
                float4 v = *(const float4*)&src[(size_t)row * NTOK + c4 * 4];
                *(float4*)&depL[row * DEPS + c4 * 4] = v;
            }
        }
    }

    f32x4 acc[32];
    #pragma unroll
    for (int t = 0; t < 32; ++t) acc[t] = (f32x4){0.f, 0.f, 0.f, 0.f};

    // Q as B-fragment: B[col=l15 -> q row][k=quad*8+j]; Q pre-scaled 0.9/8 in proj
    const f16* __restrict__ Qb = QK + (size_t)(b * NTOK + q0 + l15) * 1536 + h * 64 + quad * 8;
    const f16x8 qf0 = *(const f16x8*)(Qb);
    const f16x8 qf1 = *(const f16x8*)(Qb + 32);

    // K as A-fragment: A[row=l15 -> key within tile][k=quad*8+j], from L2
    const f16* __restrict__ Kb = QK + (size_t)(b * NTOK + l15) * 1536 + 768 + h * 64 + quad * 8;
    #pragma unroll
    for (int t = 0; t < 32; ++t) {
        f16x8 k0 = *(const f16x8*)(Kb + (size_t)(t * 16) * 1536);
        acc[t] = __builtin_amdgcn_mfma_f32_16x16x32_f16(k0, qf0, acc[t], 0, 0, 0);
        f16x8 k1 = *(const f16x8*)(Kb + (size_t)(t * 16) * 1536 + 32);
        acc[t] = __builtin_amdgcn_mfma_f32_16x16x32_f16(k1, qf1, acc[t], 0, 0, 0);
    }

    __syncthreads();   // dep tile staged by all waves

    // blend (float4 dep from LDS) + mask + row-max, single pass.
    // lane's k for (t, r) = t*16 + quad*4 + r
    const float DW = 0.1f;
    const int* __restrict__ mrow = mask + b * NTOK;
    float m = NEGV;
    #pragma unroll
    for (int t = 0; t < 32; ++t) {
        const int kc = t * 16 + quad * 4;
        const f32x4 dv = *(const f32x4*)&depL[l15 * DEPS + kc];
        const int4  mv = *(const int4*)&mrow[kc];
        const float s0 = acc[t][0] + DW * dv[0];
        const float s1 = acc[t][1] + DW * dv[1];
        const float s2 = acc[t][2] + DW * dv[2];
        const float s3 = acc[t][3] + DW * dv[3];
        acc[t][0] = mv.x ? s0 : NEGV;
        acc[t][1] = mv.y ? s1 : NEGV;
        acc[t][2] = mv.z ? s2 : NEGV;
        acc[t][3] = mv.w ? s3 : NEGV;
        m = fmaxf(m, fmaxf(fmaxf(acc[t][0], acc[t][1]), fmaxf(acc[t][2], acc[t][3])));
    }
    // q row lives in lanes {l15, l15+16, l15+32, l15+48}
    m = fmaxf(m, __shfl_xor(m, 16));
    m = fmaxf(m, __shfl_xor(m, 32));

    float sum = 0.f;
    #pragma unroll
    for (int t = 0; t < 32; ++t) {
        #pragma unroll
        for (int r = 0; r < 4; ++r) {
            const float e = __expf(acc[t][r] - m);
            acc[t][r] = e;
            sum += e;
        }
    }
    sum += __shfl_xor(sum, 16);
    sum += __shfl_xor(sum, 32);
    const float inv = 1.0f / sum;

    // epilogue: direct float4 stores. out[b][h][q0+l15][16t + 4*quad + r]
    const size_t obase = ((size_t)((b * NHEAD + h) * NTOK) + q0 + l15) * NTOK + quad * 4;
    #pragma unroll
    for (int t = 0; t < 32; ++t) {
        f32x4 v = acc[t] * inv;
        *(f32x4*)&out[obase + (size_t)t * 16] = v;
    }
}

// ---------------------------------------------------------------------------
extern "C" void kernel_launch(void* const* d_in, const int* in_sizes, int n_in,
                              void* d_out, int out_size, void* d_ws, size_t ws_size,
                              hipStream_t stream) {
    const float* X    = (const float*)d_in[0];
    const int*   mask = (const int*)  d_in[1];
    const float* dep  = (const float*)d_in[2];
    const float* Wq   = (const float*)d_in[3];
    const float* bq   = (const float*)d_in[4];
    const float* Wk   = (const float*)d_in[5];
    const float* bk   = (const float*)d_in[6];
    float* out = (float*)d_out;

    f16* Xh = (f16*)d_ws;                                  // 4096*768
    f16* Wt = Xh + (size_t)BATCH * NTOK * DMODEL;          // 1536*768
    f16* QK = Wt + (size_t)1536 * DMODEL;                  // 4096*1536

    prep_kernel<<<dim3(3072 + 1152), 256, 0, stream>>>(X, Xh, Wq, Wk, Wt);
    proj_mfma<<<dim3(4096 / 128, 1536 / 128), 256, 0, stream>>>(Xh, Wt, bq, bk, QK);
    attn_mfma<<<dim3(32, 2, BATCH), 384, 0, stream>>>(QK, dep, mask, out);
}